// Round 7
// baseline (120.176 us; speedup 1.0000x reference)
//
#include <hip/hip_runtime.h>
#include <stdint.h>

#define NQ 10
#define DIMQ 1024
#define BATCH 4096

typedef float f32x2 __attribute__((ext_vector_type(2)));

// ------------------------------------------------------- gate coefficients ---
__global__ __launch_bounds__(64) void prep_g(const float* __restrict__ wts,
                                             float* __restrict__ Gg) {
  int g = threadIdx.x;
  if (g < 40) {
    float phi = wts[g * 3 + 0], th = wts[g * 3 + 1], om = wts[g * 3 + 2];
    float ct = cosf(0.5f * th), s = sinf(0.5f * th);
    float ap = 0.5f * (phi + om), am = 0.5f * (phi - om);
    float cp = cosf(ap), spp = sinf(ap), cm = cosf(am), sm = sinf(am);
    Gg[g * 8 + 0] = ct * cp;  Gg[g * 8 + 1] = -ct * spp;  // a
    Gg[g * 8 + 2] = -s * cm;  Gg[g * 8 + 3] = -s * sm;    // b
    Gg[g * 8 + 4] = s * cm;   Gg[g * 8 + 5] = -s * sm;    // c
    Gg[g * 8 + 6] = ct * cp;  Gg[g * 8 + 7] = ct * spp;   // d
  }
}

// Layer's 10 CNOTs composed as a GF(2)-linear index map (scatter form).
__host__ __device__ constexpr int cperm_c(int x, int r) {
  for (int q = 0; q < NQ; ++q) {
    const int c = 9 - q;
    int t = c - r; if (t < 0) t += NQ;
    x ^= ((x >> c) & 1) << t;
  }
  return x;
}

// ---- VALU-pipe lane shuffles (R6 post-mortem: all __shfl_xor lower to
// ds_bpermute on the shared per-CU DS pipe; ~930 DS ops/row on the serial
// gate chain was the latency wall. DPP/permlane are VALU-pipe.) ----
template<int CTRL>
__device__ __forceinline__ float dpp1(float x) {
  return __int_as_float(
      __builtin_amdgcn_update_dpp(0, __float_as_int(x), CTRL, 0xF, 0xF, true));
}
// DPP ctrl: quad_perm xor1=0xB1, xor2=0x4E, xor3=0x1B; row_mirror(^15)=0x140,
// row_half_mirror(^7)=0x141. Compositions: ^4 = ^7 o ^3, ^8 = ^15 o ^7.
template<int P>   // P = lane bit, 0..4
__device__ __forceinline__ f32x2 lane_shfl(f32x2 v) {
  f32x2 r;
  if constexpr (P == 0)      { r.x = dpp1<0xB1>(v.x); r.y = dpp1<0xB1>(v.y); }
  else if constexpr (P == 1) { r.x = dpp1<0x4E>(v.x); r.y = dpp1<0x4E>(v.y); }
  else if constexpr (P == 2) { r.x = dpp1<0x141>(dpp1<0x1B>(v.x));
                               r.y = dpp1<0x141>(dpp1<0x1B>(v.y)); }
  else if constexpr (P == 3) { r.x = dpp1<0x140>(dpp1<0x141>(v.x));
                               r.y = dpp1<0x140>(dpp1<0x141>(v.y)); }
  else {                     // P == 4: xor16, ds_swizzle (within-32 ok)
    r.x = __int_as_float(__builtin_amdgcn_ds_swizzle(__float_as_int(v.x), 0x401F));
    r.y = __int_as_float(__builtin_amdgcn_ds_swizzle(__float_as_int(v.y), 0x401F));
  }
  return r;
}

__device__ __forceinline__ f32x2 cswap(f32x2 v) {  // i*(x+iy) partner: (-y, x)
  f32x2 r; r.x = -v.y; r.y = v.x; return r;
}

// Register-bit rotation (bits 9:6). Packed f32x2 complex math.
template<int MT>
__device__ __forceinline__ void rotR(f32x2 (&s)[16], const float* __restrict__ G) {
  const float G0=G[0],G1=G[1],G2=G[2],G3=G[3],G4=G[4],G5=G[5],G6=G[6],G7=G[7];
  #pragma unroll
  for (int e0 = 0; e0 < 16; ++e0) {
    if (e0 & MT) continue;
    const int e1 = e0 | MT;
    f32x2 x0 = s[e0], x1 = s[e1], n0 = cswap(x0), n1 = cswap(x1);
    s[e0] = G0*x0 + G1*n0 + G2*x1 + G3*n1;
    s[e1] = G4*x0 + G5*n0 + G6*x1 + G7*n1;
  }
}

// Lane-bit rotation, bits 0..4 (DPP / swizzle partner).
template<int P>
__device__ __forceinline__ void rotL(f32x2 (&s)[16], const float* __restrict__ G,
                                     int lane) {
  const int L = (lane >> P) & 1;
  const float aR = L ? G[6] : G[0], aI = L ? G[7] : G[1];
  const float bR = L ? G[4] : G[2], bI = L ? G[5] : G[3];
  #pragma unroll
  for (int e = 0; e < 16; ++e) {
    f32x2 o = lane_shfl<P>(s[e]);
    s[e] = aR*s[e] + aI*cswap(s[e]) + bR*o + bI*cswap(o);
  }
}

// Lane-bit 5 (xor32): v_permlane32_swap (VALU). With (x,x) it returns
// r[0]=low-half value in all lanes, r[1]=high-half value in all lanes.
__device__ __forceinline__ void rot5(f32x2 (&s)[16], const float* __restrict__ G,
                                     int lane) {
  const int L = lane >> 5;
  const float aR = L ? G[6] : G[0], aI = L ? G[7] : G[1];
  const float bR = L ? G[4] : G[2], bI = L ? G[5] : G[3];
  #pragma unroll
  for (int e = 0; e < 16; ++e) {
    unsigned xr = __float_as_uint(s[e].x), xi = __float_as_uint(s[e].y);
    auto rr = __builtin_amdgcn_permlane32_swap(xr, xr, false, false);
    auto ri = __builtin_amdgcn_permlane32_swap(xi, xi, false, false);
    f32x2 o;
    o.x = __uint_as_float(L ? rr[0] : rr[1]);
    o.y = __uint_as_float(L ? ri[0] : ri[1]);
    s[e] = aR*s[e] + aI*cswap(s[e]) + bR*o + bI*cswap(o);
  }
}

// CNOT permutation via private LDS slice (same-wave DS in-order, no barrier).
template<int R>
__device__ __forceinline__ void perm_state(f32x2 (&s)[16], f32x2* __restrict__ L,
                                           int lane) {
  constexpr int K0=cperm_c(1,R),  K1=cperm_c(2,R),  K2=cperm_c(4,R),
                K3=cperm_c(8,R),  K4=cperm_c(16,R), K5=cperm_c(32,R),
                C6=cperm_c(64,R), C7=cperm_c(128,R),
                C8=cperm_c(256,R),C9=cperm_c(512,R);
  const int yl = ((lane & 1)  ? K0 : 0) ^ ((lane & 2)  ? K1 : 0) ^
                 ((lane & 4)  ? K2 : 0) ^ ((lane & 8)  ? K3 : 0) ^
                 ((lane & 16) ? K4 : 0) ^ ((lane & 32) ? K5 : 0);
  #pragma unroll
  for (int e = 0; e < 16; ++e) {
    const int ye = ((e & 1) ? C6 : 0) ^ ((e & 2) ? C7 : 0) ^
                   ((e & 4) ? C8 : 0) ^ ((e & 8) ? C9 : 0);
    L[yl ^ ye] = s[e];
  }
  #pragma unroll
  for (int e = 0; e < 16; ++e) s[e] = L[(e << 6) | lane];
}

template<int LYR>
__device__ __forceinline__ void do_layer(f32x2 (&s)[16], const float* __restrict__ Gg,
                                         f32x2* __restrict__ L, int lane) {
  const float* Gl = Gg + LYR * 80;
  rotR<8>(s, Gl + 0);          // q0 -> bit9
  rotR<4>(s, Gl + 8);          // q1 -> bit8
  rotR<2>(s, Gl + 16);         // q2 -> bit7
  rotR<1>(s, Gl + 24);         // q3 -> bit6
  rot5   (s, Gl + 32, lane);   // q4 -> bit5 (permlane32_swap)
  rotL<4>(s, Gl + 40, lane);   // q5 -> bit4 (ds_swizzle xor16)
  rotL<3>(s, Gl + 48, lane);   // q6 -> bit3 (DPP)
  rotL<2>(s, Gl + 56, lane);   // q7 -> bit2 (DPP)
  rotL<1>(s, Gl + 64, lane);   // q8 -> bit1 (DPP)
  rotL<0>(s, Gl + 72, lane);   // q9 -> bit0 (DPP)
  if constexpr (LYR < 3) perm_state<LYR + 1>(s, L, lane);
  // layer 3's permutation (r=4) is folded into the epilogue sign masks
}

// Wave sum -> uniform scalar: DPP tree for ^1..^8, swizzle ^16, readlane pair.
__device__ __forceinline__ float red64(float v) {
  v += dpp1<0xB1>(v);
  v += dpp1<0x4E>(v);
  v += dpp1<0x141>(dpp1<0x1B>(v));   // ^4
  v += dpp1<0x140>(dpp1<0x141>(v));  // ^8
  v += __int_as_float(__builtin_amdgcn_ds_swizzle(__float_as_int(v), 0x401F));
  float lo = __int_as_float(__builtin_amdgcn_readlane(__float_as_int(v), 0));
  float hi = __int_as_float(__builtin_amdgcn_readlane(__float_as_int(v), 32));
  return lo + hi;
}

// ------------------------------------------------------- fused simulation ---
// One row per wave, 16 complex amps/lane, idx=(e<<6)|lane. All shuffles on
// the VALU pipe except xor16 + the 3 CNOT perms. Zero __syncthreads.
// Grid caps occupancy at 4 waves/SIMD, so launch_bounds(256,2) (128-VGPR
// budget) costs nothing and frees the allocator (R3/R4 lesson).
__global__ __launch_bounds__(256, 2) void vqc_sim(const float* __restrict__ X,
                                                  const float* __restrict__ Gg,
                                                  const float* __restrict__ W,
                                                  const float* __restrict__ bias,
                                                  float* __restrict__ out) {
  __shared__ f32x2 lds[4][DIMQ];     // 32 KB -> 4 blocks/CU
  const int lane = threadIdx.x & 63;
  const int w = threadIdx.x >> 6;
  const int row = blockIdx.x * 4 + w;
  f32x2* L = lds[w];

  f32x2 s[16];

  // ---- load (coalesced; norm deferred) ----
  const float* xr = X + (size_t)row * DIMQ;
  float ss = 0.f;
  #pragma unroll
  for (int e = 0; e < 16; ++e) {
    s[e].x = xr[(e << 6) | lane];
    s[e].y = 0.f;
    ss += s[e].x * s[e].x;
  }
  const float rn2 = 1.0f / red64(ss);   // uniform probability scale

  do_layer<0>(s, Gg, L, lane);
  do_layer<1>(s, Gg, L, lane);
  do_layer<2>(s, Gg, L, lane);
  do_layer<3>(s, Gg, L, lane);

  // ---- probs -> z (layer-3 perm r=4 folded into signs) ----
  constexpr int R4 = 4;
  constexpr int K0=cperm_c(1,R4),  K1=cperm_c(2,R4),  K2=cperm_c(4,R4),
                K3=cperm_c(8,R4),  K4=cperm_c(16,R4), K5=cperm_c(32,R4),
                C6=cperm_c(64,R4), C7=cperm_c(128,R4),
                C8=cperm_c(256,R4),C9=cperm_c(512,R4);
  const int yl = ((lane & 1)  ? K0 : 0) ^ ((lane & 2)  ? K1 : 0) ^
                 ((lane & 4)  ? K2 : 0) ^ ((lane & 8)  ? K3 : 0) ^
                 ((lane & 16) ? K4 : 0) ^ ((lane & 32) ? K5 : 0);
  float z[10];
  #pragma unroll
  for (int q = 0; q < 10; ++q) z[q] = 0.f;
  #pragma unroll
  for (int e = 0; e < 16; ++e) {
    const int y = yl ^ (((e & 1) ? C6 : 0) ^ ((e & 2) ? C7 : 0) ^
                        ((e & 4) ? C8 : 0) ^ ((e & 8) ? C9 : 0));
    const float pr = s[e].x * s[e].x + s[e].y * s[e].y;
    #pragma unroll
    for (int q = 0; q < 10; ++q)
      z[q] += ((y >> (9 - q)) & 1) ? -pr : pr;
  }
  #pragma unroll
  for (int q = 0; q < 10; ++q) z[q] = red64(z[q]) * rn2;   // uniform

  // ---- linear head ----
  if (lane < 16) {
    float acc = bias[lane];
    #pragma unroll
    for (int q = 0; q < 10; ++q) acc += z[q] * W[lane * 10 + q];
    out[(size_t)row * 16 + lane] = acc;
  }
}

extern "C" void kernel_launch(void* const* d_in, const int* in_sizes, int n_in,
                              void* d_out, int out_size, void* d_ws, size_t ws_size,
                              hipStream_t stream) {
  const float* X    = (const float*)d_in[0];
  const float* wts  = (const float*)d_in[1];
  const float* W    = (const float*)d_in[2];
  const float* bias = (const float*)d_in[3];
  float* out = (float*)d_out;
  float* Gg = (float*)d_ws;   // 40 gates x 8 coeffs = 1.25 KB

  hipLaunchKernelGGL(prep_g,  dim3(1),         dim3(64),  0, stream, wts, Gg);
  hipLaunchKernelGGL(vqc_sim, dim3(BATCH / 4), dim3(256), 0, stream, X, Gg, W, bias, out);
}